// Round 3
// baseline (243.498 us; speedup 1.0000x reference)
//
#include <hip/hip_runtime.h>

#define Bn 8
#define Nn 4096
#define Pn 4096
#define Kn 32
#define Cn 128

using float4v = __attribute__((ext_vector_type(4))) float;
using short8  = __attribute__((ext_vector_type(8))) short;

__device__ __forceinline__ unsigned short bf16b(float f) {
  union { float f; unsigned u; } v; v.f = f;
  unsigned r = v.u + 0x7FFFu + ((v.u >> 16) & 1u);   // round-nearest-even
  return (unsigned short)(r >> 16);
}

// (hi16(x)) | (hi16(y)<<16) — truncating f32->bf16 pair pack, one v_perm_b32
__device__ __forceinline__ unsigned pkhi(float x, float y) {
  return __builtin_amdgcn_perm(__float_as_uint(y), __float_as_uint(x), 0x07060302u);
}

// ---------------------------------------------------------------------------
// prep: blocks 0-15: WlT[n][k] = bf16(Wl[k][n]); blocks 16-47: xyz copy into
// d_out (+ block 16 zeroes gacc).
// ---------------------------------------------------------------------------
__global__ __launch_bounds__(256) void prep(const float* __restrict__ Wl,
                                            unsigned short* __restrict__ WlT,
                                            const float* __restrict__ xyz,
                                            float* __restrict__ out,
                                            float* __restrict__ gacc) {
  __shared__ unsigned short tile[128 * 130];
  const int t = threadIdx.x, blk = blockIdx.x;
  if (blk < 16) {
#pragma unroll
    for (int i = 0; i < 64; ++i) {
      int idx = i * 256 + t;
      int kl = idx >> 7, n = idx & 127;
      tile[n * 130 + kl] = bf16b(Wl[(size_t)(blk * 128 + kl) * 128 + n]);
    }
    __syncthreads();
#pragma unroll
    for (int i = 0; i < 64; ++i) {
      int idx = i * 256 + t;
      int n = idx >> 7, kl = idx & 127;
      WlT[(size_t)n * 2048 + blk * 128 + kl] = tile[n * 130 + kl];
    }
  } else {
    if (blk == 16) gacc[t] = 0.f;
    const int i0 = (blk - 16) * 3072 + t * 12;   // 32 blocks x 3072 f32 = 98304
#pragma unroll
    for (int i = 0; i < 3; ++i)
      *(float4v*)(out + i0 + i * 4) = *(const float4v*)(xyz + i0 + i * 4);
  }
}

// ---------------------------------------------------------------------------
// fused: 512 blocks x 8 waves x 64 points, double-buffered Mlds, software-
// pipelined ct loop (one barrier per ct). Per ct: issue next chunk's gathers
// early (reg-staged), run step2 MFMAs on current buffer to cover latency,
// finish (pack + step1 MFMA + ds_write) into the other buffer. nlds holds
// pre-shifted (<<9) neighbor byte offsets. setprio(1) around MFMA clusters.
// Accumulation order identical to round-2 fused -> same numerics.
// ---------------------------------------------------------------------------
__global__ __launch_bounds__(512, 4) void fused(
    const float* __restrict__ points, const float* __restrict__ lc,
    const int* __restrict__ nl, const int* __restrict__ didx,
    const float* __restrict__ Ww, const float* __restrict__ bwv,
    const unsigned short* __restrict__ WlT, const float* __restrict__ blv,
    float* __restrict__ xout, float* __restrict__ gacc) {
  __shared__ unsigned short Mlds[2][64 * 256];   // 2 x 32 KB, row-XOR-swizzled
  __shared__ int nlds[64 * 32];                  // 8 KB, pre-shifted ids
  __shared__ float red[256];

  const int t = threadIdx.x, lane = t & 63, w = t >> 6;
  const int l15 = lane & 15, q = lane >> 4;
  const int b = blockIdx.x & 7;                  // XCD-affine batch
  const int pg = blockIdx.x >> 3;                // 0..63
  const int p0 = pg * 64;
  const int db = didx[b];
  const char* __restrict__ pbase = (const char*)(points + (size_t)db * Nn * Cn);

  // stage neighbor ids (pre-shifted to byte row offsets)
  {
    int4 nv = *(const int4*)(nl + (size_t)(db * Pn + p0) * Kn + t * 4);
    nv.x <<= 9; nv.y <<= 9; nv.z <<= 9; nv.w <<= 9;
    *(int4*)&nlds[t * 4] = nv;
  }

  const float Ww0 = Ww[l15], Ww1 = Ww[16 + l15], Ww2 = Ww[32 + l15];
  const float bw0 = bwv[l15];

  // weight A-frags for my 8 points: A[m=w_out=l15][k=q*8+j]
  short8 af[8];
#pragma unroll
  for (int i = 0; i < 8; ++i) {
    const int p = p0 + w * 8 + i;
    const int pk = (db * Pn + p) * Kn;
    const float* __restrict__ lcp = lc + (size_t)(pk + q * 8) * 3;
    float la[24];
#pragma unroll
    for (int v = 0; v < 6; ++v) *(float4v*)&la[v * 4] = *(const float4v*)(lcp + v * 4);
#pragma unroll
    for (int j = 0; j < 8; ++j) {
      float ww = bw0 + la[3 * j] * Ww0 + la[3 * j + 1] * Ww1 + la[3 * j + 2] * Ww2;
      af[i][j] = (short)bf16b(ww);
    }
  }

  float4v acc[4];
#pragma unroll
  for (int rg = 0; rg < 4; ++rg) acc[rg] = (float4v){0.f, 0.f, 0.f, 0.f};

  __syncthreads();   // nlds ready

  // my n-slice: channels w*16 .. w*16+15 (lane l15 -> channel)
  const unsigned short* __restrict__ bp =
      WlT + (size_t)(w * 16 + l15) * 2048 + q * 8;
  const unsigned cvoff = (unsigned)(l15 * 4);    // channel byte within 64B slice

// issue 8 gathers for point (i), chunk (ct) into fdst[8]
#define GATHER(i, ct, fdst)                                                \
  {                                                                        \
    const int pi_ = w * 8 + (i);                                           \
    int nk_[8];                                                            \
    *(int4*)&nk_[0] = *(const int4*)&nlds[pi_ * 32 + q * 8];               \
    *(int4*)&nk_[4] = *(const int4*)&nlds[pi_ * 32 + q * 8 + 4];           \
    _Pragma("unroll") for (int j = 0; j < 8; ++j)                          \
        fdst[j] = *(const float*)(pbase + ((unsigned)nk_[j] + cvoff +      \
                                           (unsigned)((ct) * 64)));        \
  }

// pack + step1 MFMA + swizzled ds_write for point (i) into buffer (bsel)
#define FINISH(i, bsel, fsrc)                                              \
  {                                                                        \
    const int pi_ = w * 8 + (i);                                           \
    union { short8 s; unsigned u[4]; } bv_;                                \
    bv_.u[0] = pkhi(fsrc[0], fsrc[1]);                                     \
    bv_.u[1] = pkhi(fsrc[2], fsrc[3]);                                     \
    bv_.u[2] = pkhi(fsrc[4], fsrc[5]);                                     \
    bv_.u[3] = pkhi(fsrc[6], fsrc[7]);                                     \
    float4v d_ = {0.f, 0.f, 0.f, 0.f};                                     \
    d_ = __builtin_amdgcn_mfma_f32_16x16x32_bf16(af[i], bv_.s, d_, 0, 0, 0); \
    const unsigned off_ = (unsigned)((bsel) * 32768 + pi_ * 512 +          \
        ((l15 * 32 + q * 8) ^ ((pi_ & 7) << 4)));                          \
    uint2 u_;                                                              \
    u_.x = pkhi(d_[0], d_[1]);                                             \
    u_.y = pkhi(d_[2], d_[3]);                                             \
    *(uint2*)((char*)Mlds + off_) = u_;                                    \
  }

// step2 for one ks: 4 A-frag LDS reads + 4 MFMAs (B-frag given)
#define STEP2KS(ks, bsel, bfrag)                                           \
  {                                                                        \
    const char* mb_ = (const char*)Mlds + (bsel) * 32768;                  \
    const unsigned ax_ = (unsigned)(((ks) * 64 + q * 16) ^ ((l15 & 7) << 4)); \
    short8 a0_ = *(const short8*)(mb_ + (l15) * 512 + ax_);                \
    short8 a1_ = *(const short8*)(mb_ + (16 + l15) * 512 + ax_);           \
    short8 a2_ = *(const short8*)(mb_ + (32 + l15) * 512 + ax_);           \
    short8 a3_ = *(const short8*)(mb_ + (48 + l15) * 512 + ax_);           \
    acc[0] = __builtin_amdgcn_mfma_f32_16x16x32_bf16(a0_, bfrag, acc[0], 0, 0, 0); \
    acc[1] = __builtin_amdgcn_mfma_f32_16x16x32_bf16(a1_, bfrag, acc[1], 0, 0, 0); \
    acc[2] = __builtin_amdgcn_mfma_f32_16x16x32_bf16(a2_, bfrag, acc[2], 0, 0, 0); \
    acc[3] = __builtin_amdgcn_mfma_f32_16x16x32_bf16(a3_, bfrag, acc[3], 0, 0, 0); \
  }

  // prologue: step1 for ct=0 into buffer 0 (all 64 gathers in flight)
  {
    float f0[8][8];
#pragma unroll
    for (int i = 0; i < 8; ++i) GATHER(i, 0, f0[i])
#pragma unroll
    for (int i = 0; i < 8; ++i) FINISH(i, 0, f0[i])
  }
  __syncthreads();

#pragma unroll
  for (int ct = 0; ct < 8; ++ct) {
    const int cur = ct & 1, nxt = cur ^ 1;
    // B-frags first half (counted prefetch; L2-resident WlT)
    short8 bqA[4];
#pragma unroll
    for (int ks = 0; ks < 4; ++ks)
      bqA[ks] = *(const short8*)(bp + ct * 256 + ks * 32);
    // issue gathers for next chunk, points 0-3 (latency hidden by step2)
    float fA[4][8];
    if (ct < 7) {
#pragma unroll
      for (int i = 0; i < 4; ++i) GATHER(i, ct + 1, fA[i])
    }
    __builtin_amdgcn_s_setprio(1);
    STEP2KS(0, cur, bqA[0])
    STEP2KS(1, cur, bqA[1])
    STEP2KS(2, cur, bqA[2])
    STEP2KS(3, cur, bqA[3])
    __builtin_amdgcn_s_setprio(0);
    // B-frags second half
    short8 bqB[4];
#pragma unroll
    for (int ks = 0; ks < 4; ++ks)
      bqB[ks] = *(const short8*)(bp + ct * 256 + 128 + ks * 32);
    float fB[4][8];
    if (ct < 7) {
#pragma unroll
      for (int i = 0; i < 4; ++i) FINISH(i, nxt, fA[i])
#pragma unroll
      for (int i = 0; i < 4; ++i) GATHER(4 + i, ct + 1, fB[i])
    }
    __builtin_amdgcn_s_setprio(1);
    STEP2KS(4, cur, bqB[0])
    STEP2KS(5, cur, bqB[1])
    STEP2KS(6, cur, bqB[2])
    STEP2KS(7, cur, bqB[3])
    __builtin_amdgcn_s_setprio(0);
    if (ct < 7) {
#pragma unroll
      for (int i = 0; i < 4; ++i) FINISH(4 + i, nxt, fB[i])
    }
    __syncthreads();
  }
#undef GATHER
#undef FINISH
#undef STEP2KS

  // epilogue: bias, transposed store (B,C,P), disjoint per-wave channel stats
  {
    const int ch = w * 16 + l15;
    const float bb = blv[ch];
    float s = 0.f, sq = 0.f;
#pragma unroll
    for (int rg = 0; rg < 4; ++rg) {
      float4v o;
#pragma unroll
      for (int r = 0; r < 4; ++r) {
        float v = acc[rg][r] + bb; o[r] = v; s += v; sq += v * v;
      }
      *(float4v*)(xout + ((size_t)(b * Cn + ch)) * Pn + p0 + rg * 16 + q * 4) = o;
    }
    s += __shfl_xor(s, 16); s += __shfl_xor(s, 32);
    sq += __shfl_xor(sq, 16); sq += __shfl_xor(sq, 32);
    if (lane < 16) { red[ch] = s; red[128 + ch] = sq; }
  }
  __syncthreads();
  if (t < 256) atomicAdd(&gacc[t], red[t]);
}

// ---------------------------------------------------------------------------
// finalize: layernorm (per-channel over B*P) + relu, in place on x chunk
// ---------------------------------------------------------------------------
__global__ __launch_bounds__(256) void finalize_ln(float* __restrict__ x,
                                                   const float* __restrict__ gacc,
                                                   const float* __restrict__ gamma,
                                                   const float* __restrict__ beta) {
  const int idx = blockIdx.x * 256 + threadIdx.x;
  const int fi = idx * 4;
  const int c = (fi >> 12) & 127;
  const float inv = 1.f / 32768.f;
  const float mean = gacc[c] * inv;
  const float var = gacc[128 + c] * inv - mean * mean;
  const float scale = rsqrtf(var + 1e-5f) * gamma[c];
  const float shift = beta[c] - mean * scale;
  float4v v = *(float4v*)(x + fi);
#pragma unroll
  for (int r = 0; r < 4; ++r) v[r] = fmaxf(v[r] * scale + shift, 0.f);
  *(float4v*)(x + fi) = v;
}

extern "C" void kernel_launch(void* const* d_in, const int* in_sizes, int n_in,
                              void* d_out, int out_size, void* d_ws, size_t ws_size,
                              hipStream_t stream) {
  const float* xyz    = (const float*)d_in[0];
  const float* points = (const float*)d_in[1];
  const float* lc     = (const float*)d_in[2];
  const int*   nl     = (const int*)d_in[3];
  const int*   didx   = (const int*)d_in[4];
  const float* Ww     = (const float*)d_in[5];
  const float* bw     = (const float*)d_in[6];
  const float* Wl     = (const float*)d_in[7];
  const float* bl     = (const float*)d_in[8];
  const float* gamma  = (const float*)d_in[9];
  const float* beta   = (const float*)d_in[10];

  float* out  = (float*)d_out;
  float* xout = out + (size_t)Bn * Pn * 3;                       // x chunk (B,C,P)
  unsigned short* WlT = (unsigned short*)d_ws;                   // 512 KB
  float* gacc = (float*)((char*)d_ws + (size_t)512 * 1024);      // 1 KB

  prep<<<48, 256, 0, stream>>>(Wl, WlT, xyz, out, gacc);
  fused<<<512, 512, 0, stream>>>(points, lc, nl, didx, Ww, bw, WlT, bl,
                                 xout, gacc);
  finalize_ln<<<4096, 256, 0, stream>>>(xout, gacc, gamma, beta);
}

// Round 4
// 193.237 us; speedup vs baseline: 1.2601x; 1.2601x over previous
//
#include <hip/hip_runtime.h>

#define Bn 8
#define Nn 4096
#define Pn 4096
#define Kn 32
#define Cn 128

using float4v = __attribute__((ext_vector_type(4))) float;
using short8  = __attribute__((ext_vector_type(8))) short;

__device__ __forceinline__ unsigned short bf16b(float f) {
  union { float f; unsigned u; } v; v.f = f;
  unsigned r = v.u + 0x7FFFu + ((v.u >> 16) & 1u);   // round-nearest-even
  return (unsigned short)(r >> 16);
}

// (hi16(x)) | (hi16(y)<<16) — truncating f32->bf16 pair pack, one v_perm_b32
__device__ __forceinline__ unsigned pkhi(float x, float y) {
  return __builtin_amdgcn_perm(__float_as_uint(y), __float_as_uint(x), 0x07060302u);
}

// ---------------------------------------------------------------------------
// prep: blocks 0-15: WlT[n][k] = bf16(Wl[k][n]); blocks 16-47: xyz copy into
// d_out (+ block 16 zeroes gacc).
// ---------------------------------------------------------------------------
__global__ __launch_bounds__(256) void prep(const float* __restrict__ Wl,
                                            unsigned short* __restrict__ WlT,
                                            const float* __restrict__ xyz,
                                            float* __restrict__ out,
                                            float* __restrict__ gacc) {
  __shared__ unsigned short tile[128 * 130];
  const int t = threadIdx.x, blk = blockIdx.x;
  if (blk < 16) {
#pragma unroll
    for (int i = 0; i < 64; ++i) {
      int idx = i * 256 + t;
      int kl = idx >> 7, n = idx & 127;
      tile[n * 130 + kl] = bf16b(Wl[(size_t)(blk * 128 + kl) * 128 + n]);
    }
    __syncthreads();
#pragma unroll
    for (int i = 0; i < 64; ++i) {
      int idx = i * 256 + t;
      int n = idx >> 7, kl = idx & 127;
      WlT[(size_t)n * 2048 + blk * 128 + kl] = tile[n * 130 + kl];
    }
  } else {
    if (blk == 16) gacc[t] = 0.f;
    const int i0 = (blk - 16) * 3072 + t * 12;   // 32 blocks x 3072 f32 = 98304
#pragma unroll
    for (int i = 0; i < 3; ++i)
      *(float4v*)(out + i0 + i * 4) = *(const float4v*)(xyz + i0 + i * 4);
  }
}

// ---------------------------------------------------------------------------
// fused (round-2 structure + register headroom + bounded gather pipeline):
// 1024 blocks x 4 waves x 32 points, single Mlds, 2 barriers per ct.
// amdgpu_waves_per_eu(4,4) caps occupancy at 4 waves/EU (grid is 4 blocks/CU
// anyway) -> 128-VGPR budget instead of 64. Phase B uses a 4-point lookahead
// ring fb[4][8] (32 transient VGPRs, static indices): 32 gathers in flight
// instead of 8-and-drain. vmem phases disjoint -> compiler waitcnts stay
// correct, no inline asm. Accumulation order identical to round 2.
// ---------------------------------------------------------------------------
__attribute__((amdgpu_waves_per_eu(4, 4)))
__global__ __launch_bounds__(256) void fused(
    const float* __restrict__ points, const float* __restrict__ lc,
    const int* __restrict__ nl, const int* __restrict__ didx,
    const float* __restrict__ Ww, const float* __restrict__ bwv,
    const unsigned short* __restrict__ WlT, const float* __restrict__ blv,
    float* __restrict__ xout, float* __restrict__ gacc) {
  __shared__ unsigned short Mlds[32 * 256];   // 16 KB, row-XOR-swizzled
  __shared__ int nlds[32 * 32];               // 4 KB, pre-shifted byte offsets
  __shared__ float red[256];

  const int t = threadIdx.x, lane = t & 63, w = t >> 6;
  const int l15 = lane & 15, q = lane >> 4;
  const int b = blockIdx.x & 7;               // XCD-affine batch
  const int pg = blockIdx.x >> 3;             // 0..127
  const int p0 = pg * 32;
  const int db = didx[b];
  const char* __restrict__ pbase = (const char*)(points + (size_t)db * Nn * Cn);

  // stage neighbor ids, pre-shifted to byte row offsets (row stride 512 B)
  {
    int4 nv = *(const int4*)(nl + (size_t)(db * Pn + p0) * Kn + t * 4);
    nv.x <<= 9; nv.y <<= 9; nv.z <<= 9; nv.w <<= 9;
    *(int4*)&nlds[t * 4] = nv;
  }

  const float Ww0 = Ww[l15], Ww1 = Ww[16 + l15], Ww2 = Ww[32 + l15];
  const float bw0 = bwv[l15];

  // weight A-frags for my 8 points: A[m=w_out=l15][k=q*8+j]
  short8 af[8];
#pragma unroll
  for (int i = 0; i < 8; ++i) {
    const int p = p0 + w * 8 + i;
    const int pk = (db * Pn + p) * Kn;
    const float* __restrict__ lcp = lc + (size_t)(pk + q * 8) * 3;
    float la[24];
#pragma unroll
    for (int v = 0; v < 6; ++v) *(float4v*)&la[v * 4] = *(const float4v*)(lcp + v * 4);
#pragma unroll
    for (int j = 0; j < 8; ++j) {
      float ww = bw0 + la[3 * j] * Ww0 + la[3 * j + 1] * Ww1 + la[3 * j + 2] * Ww2;
      af[i][j] = (short)bf16b(ww);
    }
  }

  float4v acc[2][2];
#pragma unroll
  for (int pt = 0; pt < 2; ++pt)
#pragma unroll
    for (int nt = 0; nt < 2; ++nt) acc[pt][nt] = (float4v){0.f, 0.f, 0.f, 0.f};

  __syncthreads();   // nlds ready

  // my n-slice: channels w*32 .. w*32+31
  const unsigned short* __restrict__ bpt =
      WlT + (size_t)(w * 32 + l15) * 2048 + q * 8;
  const unsigned cvoff = (unsigned)(l15 * 4);

// issue 8 gathers for point (i), chunk (ct) into fdst[8]
#define ISSUE(i, ct, fdst)                                                 \
  {                                                                        \
    const int pi_ = w * 8 + (i);                                           \
    int nk_[8];                                                            \
    *(int4*)&nk_[0] = *(const int4*)&nlds[pi_ * 32 + q * 8];               \
    *(int4*)&nk_[4] = *(const int4*)&nlds[pi_ * 32 + q * 8 + 4];           \
    _Pragma("unroll") for (int j = 0; j < 8; ++j)                          \
        fdst[j] = *(const float*)(pbase + ((unsigned)nk_[j] + cvoff +      \
                                           (unsigned)((ct) * 64)));        \
  }

// pack + step1 MFMA + swizzled ds_write for point (i)
#define FIN(i, fsrc)                                                       \
  {                                                                        \
    const int pi_ = w * 8 + (i);                                           \
    union { short8 s; unsigned u[4]; } bv_;                                \
    bv_.u[0] = pkhi(fsrc[0], fsrc[1]);                                     \
    bv_.u[1] = pkhi(fsrc[2], fsrc[3]);                                     \
    bv_.u[2] = pkhi(fsrc[4], fsrc[5]);                                     \
    bv_.u[3] = pkhi(fsrc[6], fsrc[7]);                                     \
    float4v d_ = {0.f, 0.f, 0.f, 0.f};                                     \
    d_ = __builtin_amdgcn_mfma_f32_16x16x32_bf16(af[i], bv_.s, d_, 0, 0, 0); \
    const unsigned off_ = (unsigned)(pi_ * 512 +                           \
        ((l15 * 32 + q * 8) ^ ((pi_ & 7) << 4)));                          \
    uint2 u_;                                                              \
    u_.x = pkhi(d_[0], d_[1]);                                             \
    u_.y = pkhi(d_[2], d_[3]);                                             \
    *(uint2*)((char*)Mlds + off_) = u_;                                    \
  }

  float fb[4][8];   // 4-point lookahead ring (32 VGPRs, static indices)

  for (int ct = 0; ct < 8; ++ct) {
    // ---- phase B: step1 — M tiles for my 8 points, c-range [ct*16,+16)
    ISSUE(0, ct, fb[0])
    ISSUE(1, ct, fb[1])
    ISSUE(2, ct, fb[2])
    ISSUE(3, ct, fb[3])
#pragma unroll
    for (int i = 0; i < 8; ++i) {
      FIN(i, fb[i & 3])
      if (i + 4 < 8) ISSUE(i + 4, ct, fb[i & 3])
    }
    __syncthreads();
    // ---- phase A: step2 — Y += Mchunk @ WlT-chunk for my 32 channels
    const unsigned short* __restrict__ bp = bpt + ct * 256;
#pragma unroll
    for (int ks = 0; ks < 8; ++ks) {
      const unsigned ax = (unsigned)((ks * 64 + q * 16) ^ ((l15 & 7) << 4));
      short8 a0 = *(const short8*)((const char*)Mlds + l15 * 512 + ax);
      short8 a1 = *(const short8*)((const char*)Mlds + (16 + l15) * 512 + ax);
      short8 b0 = *(const short8*)(bp + ks * 32);
      short8 b1 = *(const short8*)(bp + 32768 + ks * 32);
      acc[0][0] = __builtin_amdgcn_mfma_f32_16x16x32_bf16(a0, b0, acc[0][0], 0, 0, 0);
      acc[0][1] = __builtin_amdgcn_mfma_f32_16x16x32_bf16(a0, b1, acc[0][1], 0, 0, 0);
      acc[1][0] = __builtin_amdgcn_mfma_f32_16x16x32_bf16(a1, b0, acc[1][0], 0, 0, 0);
      acc[1][1] = __builtin_amdgcn_mfma_f32_16x16x32_bf16(a1, b1, acc[1][1], 0, 0, 0);
    }
    __syncthreads();
  }
#undef ISSUE
#undef FIN

  // epilogue: bias, transposed store (B,C,P), disjoint per-wave channel stats
#pragma unroll
  for (int nt = 0; nt < 2; ++nt) {
    const int ch = w * 32 + nt * 16 + l15;
    const float bb = blv[ch];
    float s = 0.f, sq = 0.f;
#pragma unroll
    for (int pt = 0; pt < 2; ++pt) {
      float4v o;
#pragma unroll
      for (int r = 0; r < 4; ++r) {
        float v = acc[pt][nt][r] + bb; o[r] = v; s += v; sq += v * v;
      }
      *(float4v*)(xout + ((size_t)(b * Cn + ch)) * Pn + p0 + pt * 16 + q * 4) = o;
    }
    s += __shfl_xor(s, 16); s += __shfl_xor(s, 32);
    sq += __shfl_xor(sq, 16); sq += __shfl_xor(sq, 32);
    if (lane < 16) { red[ch] = s; red[128 + ch] = sq; }
  }
  __syncthreads();
  atomicAdd(&gacc[t], red[t]);
}

// ---------------------------------------------------------------------------
// finalize: layernorm (per-channel over B*P) + relu, in place on x chunk
// ---------------------------------------------------------------------------
__global__ __launch_bounds__(256) void finalize_ln(float* __restrict__ x,
                                                   const float* __restrict__ gacc,
                                                   const float* __restrict__ gamma,
                                                   const float* __restrict__ beta) {
  const int idx = blockIdx.x * 256 + threadIdx.x;
  const int fi = idx * 4;
  const int c = (fi >> 12) & 127;
  const float inv = 1.f / 32768.f;
  const float mean = gacc[c] * inv;
  const float var = gacc[128 + c] * inv - mean * mean;
  const float scale = rsqrtf(var + 1e-5f) * gamma[c];
  const float shift = beta[c] - mean * scale;
  float4v v = *(float4v*)(x + fi);
#pragma unroll
  for (int r = 0; r < 4; ++r) v[r] = fmaxf(v[r] * scale + shift, 0.f);
  *(float4v*)(x + fi) = v;
}

extern "C" void kernel_launch(void* const* d_in, const int* in_sizes, int n_in,
                              void* d_out, int out_size, void* d_ws, size_t ws_size,
                              hipStream_t stream) {
  const float* xyz    = (const float*)d_in[0];
  const float* points = (const float*)d_in[1];
  const float* lc     = (const float*)d_in[2];
  const int*   nl     = (const int*)d_in[3];
  const int*   didx   = (const int*)d_in[4];
  const float* Ww     = (const float*)d_in[5];
  const float* bw     = (const float*)d_in[6];
  const float* Wl     = (const float*)d_in[7];
  const float* bl     = (const float*)d_in[8];
  const float* gamma  = (const float*)d_in[9];
  const float* beta   = (const float*)d_in[10];

  float* out  = (float*)d_out;
  float* xout = out + (size_t)Bn * Pn * 3;                       // x chunk (B,C,P)
  unsigned short* WlT = (unsigned short*)d_ws;                   // 512 KB
  float* gacc = (float*)((char*)d_ws + (size_t)512 * 1024);      // 1 KB

  prep<<<48, 256, 0, stream>>>(Wl, WlT, xyz, out, gacc);
  fused<<<1024, 256, 0, stream>>>(points, lc, nl, didx, Ww, bw, WlT, bl,
                                  xout, gacc);
  finalize_ln<<<4096, 256, 0, stream>>>(xout, gacc, gamma, beta);
}